// Round 1
// baseline (117.852 us; speedup 1.0000x reference)
//
#include <hip/hip_runtime.h>

#define TT 4096
#define DD 256
#define BT 64      // output rows per block
#define HW 64      // halo window (r^65 ~ 4e-11, negligible)
#define KC 16      // k-chunk for W staging

__global__ __launch_bounds__(256, 1)
void distattn_kernel(const float* __restrict__ x,
                     const float* __restrict__ mask,
                     const float* __restrict__ Win,
                     const float* __restrict__ bin,
                     float* __restrict__ out)
{
    __shared__ float yF[BT][DD + 1];   // fwd scan, then final y = attn@x rows
    __shared__ float vW[BT * DD];      // phase1: v for output rows; phase2: W tile [DD][KC+1]
    __shared__ float wv[3 * HW];       // exp(mask/e) over window
    __shared__ float rp[3 * HW];       // r^delta table
    __shared__ float s_l[BT];          // attn row sums

    const int tid = threadIdx.x;
    const int b   = blockIdx.x >> 6;           // 64 row-blocks per batch
    const int r0  = (blockIdx.x & 63) * BT;
    const int lo  = (r0 - HW > 0) ? (r0 - HW) : 0;
    const int hi  = (r0 + BT + HW < TT) ? (r0 + BT + HW) : TT;

    const float INV_E = 0.36787944117144233f;
    const float R     = 0.69220062755534635f;  // exp(-1/e)

    if (tid < 3 * HW) {
        rp[tid] = __expf(-(float)tid * INV_E);
        int j = lo + tid;
        wv[tid] = (j < hi) ? __expf(mask[b * TT + j] * INV_E) : 0.0f;
    }
    __syncthreads();

    const float* xb = x + ((size_t)b * TT) * DD + tid;  // thread owns column tid

    // ---- phase 1: banded conv via forward/backward geometric scans ----
    {
        float f = 0.0f;
        const int jend = r0 + BT;
        for (int j = lo; j < jend; ++j) {
            float v = xb[(size_t)j * DD] * wv[j - lo];
            f = fmaf(R, f, v);
            int i = j - r0;
            if (i >= 0) { yF[i][tid] = f; vW[i * DD + tid] = v; }
        }
    }
    {
        float bb = 0.0f;
        for (int j = hi - 1; j >= r0; --j) {
            int i = j - r0;
            float v = (i < BT) ? vW[i * DD + tid]
                               : xb[(size_t)j * DD] * wv[j - lo];
            bb = fmaf(R, bb, v);
            if (i < BT) yF[i][tid] = yF[i][tid] + bb - v;   // F + B - v
        }
    }
    // attn row sums (for the bias term): threads 0..63
    if (tid < BT) {
        const int ig = r0 + tid;
        float s = 0.0f;
        const int n = hi - lo;
        for (int jj = 0; jj < n; ++jj) {
            int d = ig - (lo + jj); d = (d < 0) ? -d : d;
            s += rp[d] * wv[jj];
        }
        s_l[tid] = s;
    }

    // ---- phase 2: out[r0+i][d] = sum_k yF[i][k] * Win[d][k] + s[i]*bin[d] ----
    const int tg = tid >> 4;   // i-group: i = tg + 16m
    const int tc = tid & 15;   // d-group: d = tc + 16n
    float acc[4][16];
    #pragma unroll
    for (int m = 0; m < 4; ++m)
        #pragma unroll
        for (int n = 0; n < 16; ++n) acc[m][n] = 0.0f;

    for (int kk = 0; kk < DD; kk += KC) {
        __syncthreads();                       // also protects phase-1 vW reads on first iter
        #pragma unroll
        for (int jj = 0; jj < 16; ++jj) {      // stage W[:, kk:kk+16] as [d][kc], pad 17
            int e = tid + (jj << 8);
            int d = e >> 4, kc = e & 15;
            vW[d * (KC + 1) + kc] = Win[d * DD + kk + kc];
        }
        __syncthreads();
        #pragma unroll
        for (int kc = 0; kc < KC; ++kc) {
            float ym[4];
            #pragma unroll
            for (int m = 0; m < 4; ++m) ym[m] = yF[tg + 16 * m][kk + kc];
            #pragma unroll
            for (int n = 0; n < 16; ++n) {
                float w = vW[(tc + 16 * n) * (KC + 1) + kc];
                #pragma unroll
                for (int m = 0; m < 4; ++m)
                    acc[m][n] = fmaf(ym[m], w, acc[m][n]);
            }
        }
    }

    #pragma unroll
    for (int n = 0; n < 16; ++n) {
        float bn = bin[tc + 16 * n];
        #pragma unroll
        for (int m = 0; m < 4; ++m) {
            int i = tg + 16 * m;
            out[((size_t)b * TT + r0 + i) * DD + tc + 16 * n]
                = acc[m][n] + s_l[i] * bn;
        }
    }
}

extern "C" void kernel_launch(void* const* d_in, const int* in_sizes, int n_in,
                              void* d_out, int out_size, void* d_ws, size_t ws_size,
                              hipStream_t stream) {
    const float* x    = (const float*)d_in[0];
    const float* mask = (const float*)d_in[1];
    const float* Win  = (const float*)d_in[2];
    const float* bin  = (const float*)d_in[3];
    float* out = (float*)d_out;

    const int nb = in_sizes[0] / (TT * DD);           // batches (4)
    hipLaunchKernelGGL(distattn_kernel, dim3(nb * (TT / BT)), dim3(256), 0, stream,
                       x, mask, Win, bin, out);
}

// Round 2
// 31.120 us; speedup vs baseline: 3.7870x; 3.7870x over previous
//
#include <hip/hip_runtime.h>

#define TT 4096
#define DD 256
#define BT 64               // output rows per block
#define HW 64               // halo (r^65 ~ 4e-11, invisible at fp32)
#define WIN (BT + 2*HW)     // 192-row window
#define YP (DD + 8)         // y tile pitch (bf16) -> conflict-free b128 reads
#define WP 40               // W chunk pitch (bf16): 32 + 8 pad

typedef __attribute__((ext_vector_type(8))) short short8;
typedef __attribute__((ext_vector_type(4))) float f32x4;

__device__ __forceinline__ unsigned short f2bf(float f) {
    unsigned int u = __builtin_bit_cast(unsigned int, f);
    u += 0x7fffu + ((u >> 16) & 1u);          // round-to-nearest-even
    return (unsigned short)(u >> 16);
}
__device__ __forceinline__ float bf2f(unsigned short h) {
    unsigned int u = ((unsigned int)h) << 16;
    return __builtin_bit_cast(float, u);
}

__global__ __launch_bounds__(256, 1)
void distattn_kernel(const float* __restrict__ x,
                     const float* __restrict__ mask,
                     const float* __restrict__ Win,
                     const float* __restrict__ bin,
                     float* __restrict__ out)
{
    __shared__ unsigned short yB[BT][YP];        // y = attn@x tile, bf16  (33.8 KB)
    __shared__ unsigned short Wl[2][DD][WP];     // W k-chunks, bf16, dbuf (41 KB)
    __shared__ float wv[WIN];                    // exp(mask/e), 0 outside [0,TT)
    __shared__ float rp[WIN];                    // r^delta
    __shared__ float sp[4][BT];                  // row-sum partials
    __shared__ float s_l[BT];                    // attn row sums

    const int tid  = threadIdx.x;
    const int b    = blockIdx.x >> 6;
    const int r0   = (blockIdx.x & 63) * BT;
    const int base = r0 - HW;

    const float INV_E = 0.36787944117144233f;
    const float R     = 0.69220062755534635f;    // exp(-1/e)

    if (tid < WIN) {
        rp[tid] = __expf(-(float)tid * INV_E);
        int j = base + tid;
        wv[tid] = (j >= 0 && j < TT) ? __expf(mask[b * TT + j] * INV_E) : 0.0f;
    }
    __syncthreads();

    const float* xb = x + (size_t)b * TT * DD + tid;   // thread owns column tid

    // ---- phase 1: banded conv via fwd/bwd geometric scans (constant trip) ----
    float f = 0.0f;
    #pragma unroll 8
    for (int t = 0; t < HW; ++t) {                      // top halo
        int jc = max(base + t, 0);
        f = fmaf(R, f, xb[(size_t)jc * DD] * wv[t]);
    }
    #pragma unroll 8
    for (int t = HW; t < HW + BT; ++t) {                // main rows: store F
        int j = base + t;                               // always in [0,TT)
        f = fmaf(R, f, xb[(size_t)j * DD] * wv[t]);
        yB[t - HW][tid] = f2bf(f);
    }
    float bb = 0.0f;
    #pragma unroll 8
    for (int t = WIN - 1; t >= HW + BT; --t) {          // bottom halo
        int jc = min(base + t, TT - 1);
        bb = fmaf(R, bb, xb[(size_t)jc * DD] * wv[t]);
    }
    #pragma unroll 8
    for (int t = HW + BT - 1; t >= HW; --t) {           // main rows: y = F + B - v
        int j = base + t;
        float v = xb[(size_t)j * DD] * wv[t];
        bb = fmaf(R, bb, v);
        int i = t - HW;
        yB[i][tid] = f2bf(bf2f(yB[i][tid]) + bb - v);
    }

    // attn row sums (bias term), spread over all 4 waves
    {
        int row = tid & 63, q = tid >> 6;
        float s = 0.0f;
        #pragma unroll 8
        for (int t = 48 * q; t < 48 * (q + 1); ++t) {
            int d = row + HW - t; d = (d < 0) ? -d : d;
            s = fmaf(rp[d], wv[t], s);
        }
        sp[q][row] = s;
    }
    __syncthreads();                                    // yB + sp visible
    if (tid < BT) s_l[tid] = sp[0][tid] + sp[1][tid] + sp[2][tid] + sp[3][tid];

    // ---- phase 2: out[r0+i][:] = y @ Win^T + s ⊗ bin, bf16 MFMA ----
    auto stage = [&](int c, int bufsel) {
        #pragma unroll
        for (int it = 0; it < 8; ++it) {
            int row = (tid >> 3) + 32 * it;             // wave: 8 rows x 128B, coalesced
            int kp  = tid & 7;
            float4 w4 = *reinterpret_cast<const float4*>(&Win[row * DD + 32 * c + 4 * kp]);
            uint2 p;
            p.x = (unsigned)f2bf(w4.x) | ((unsigned)f2bf(w4.y) << 16);
            p.y = (unsigned)f2bf(w4.z) | ((unsigned)f2bf(w4.w) << 16);
            *reinterpret_cast<uint2*>(&Wl[bufsel][row][4 * kp]) = p;
        }
    };

    const int w  = tid >> 6;        // wave -> output cols [64w, 64w+64)
    const int lr = tid & 15;        // row/col within 16x16 tile
    const int lg = (tid & 63) >> 4; // k-group

    f32x4 acc[4][4];
    #pragma unroll
    for (int m = 0; m < 4; ++m)
        #pragma unroll
        for (int n = 0; n < 4; ++n) acc[m][n] = (f32x4){0.f, 0.f, 0.f, 0.f};

    stage(0, 0);
    __syncthreads();
    for (int kk = 0; kk < 8; ++kk) {
        if (kk < 7) stage(kk + 1, (kk + 1) & 1);        // prefetch next chunk
        short8 afr[4], bfr[4];
        #pragma unroll
        for (int m = 0; m < 4; ++m)
            afr[m] = *reinterpret_cast<const short8*>(&yB[16 * m + lr][kk * 32 + lg * 8]);
        #pragma unroll
        for (int n = 0; n < 4; ++n)
            bfr[n] = *reinterpret_cast<const short8*>(&Wl[kk & 1][64 * w + 16 * n + lr][lg * 8]);
        #pragma unroll
        for (int m = 0; m < 4; ++m)
            #pragma unroll
            for (int n = 0; n < 4; ++n)
                acc[m][n] = __builtin_amdgcn_mfma_f32_16x16x32_bf16(afr[m], bfr[n], acc[m][n], 0, 0, 0);
        __syncthreads();
    }

    // epilogue: C/D map col=lane&15, row=(lane>>4)*4+j  [m89-verified]
    float bcol[4];
    #pragma unroll
    for (int n = 0; n < 4; ++n) bcol[n] = bin[64 * w + 16 * n + lr];
    float* ob = out + ((size_t)b * TT + r0) * DD;
    #pragma unroll
    for (int m = 0; m < 4; ++m) {
        #pragma unroll
        for (int j = 0; j < 4; ++j) {
            int i = 16 * m + lg * 4 + j;
            float si = s_l[i];
            #pragma unroll
            for (int n = 0; n < 4; ++n)
                ob[(size_t)i * DD + 64 * w + 16 * n + lr] = acc[m][n][j] + si * bcol[n];
        }
    }
}

extern "C" void kernel_launch(void* const* d_in, const int* in_sizes, int n_in,
                              void* d_out, int out_size, void* d_ws, size_t ws_size,
                              hipStream_t stream) {
    const float* x    = (const float*)d_in[0];
    const float* mask = (const float*)d_in[1];
    const float* Win  = (const float*)d_in[2];
    const float* bin  = (const float*)d_in[3];
    float* out = (float*)d_out;

    const int nb = in_sizes[0] / (TT * DD);   // batches (4)
    hipLaunchKernelGGL(distattn_kernel, dim3(nb * (TT / BT)), dim3(256), 0, stream,
                       x, mask, Win, bin, out);
}

// Round 3
// 25.246 us; speedup vs baseline: 4.6682x; 1.2327x over previous
//
#include <hip/hip_runtime.h>

#define TT 4096
#define DD 256
#define BT 64               // output rows per block
#define HW 64               // halo (r^65 ~ 4e-11, invisible at fp32)
#define WIN (BT + 2*HW)     // 192-row window
#define YP (DD + 8)         // y tile pitch (bf16)
#define WP 40               // W chunk pitch (bf16): 32 + 8 pad

typedef __attribute__((ext_vector_type(8))) short short8;
typedef __attribute__((ext_vector_type(4))) float f32x4;

__device__ __forceinline__ unsigned short f2bf(float f) {
    unsigned int u = __builtin_bit_cast(unsigned int, f);
    u += 0x7fffu + ((u >> 16) & 1u);          // round-to-nearest-even
    return (unsigned short)(u >> 16);
}
__device__ __forceinline__ float bf2f(unsigned short h) {
    unsigned int u = ((unsigned int)h) << 16;
    return __builtin_bit_cast(float, u);
}

__global__ __launch_bounds__(512, 2)
void distattn_kernel(const float* __restrict__ x,
                     const float* __restrict__ mask,
                     const float* __restrict__ Win,
                     const float* __restrict__ bin,
                     float* __restrict__ out)
{
    __shared__ float yF[BT][DD + 1];             // fp32 forward partial (65.8 KB)
    __shared__ unsigned short yB[BT][YP];        // (B - v) partial, then final y bf16 (33.8 KB)
    __shared__ unsigned short Wl[2][DD][WP];     // W k-chunks bf16, dbuf (41 KB)
    __shared__ float wv[WIN];                    // exp(mask/e), 0 outside [0,TT)
    __shared__ float rp[WIN];                    // r^delta
    __shared__ float sp[8][BT];                  // row-sum partials
    __shared__ float s_l[BT];                    // attn row sums

    const int tid  = threadIdx.x;
    const int b    = blockIdx.x >> 6;
    const int r0   = (blockIdx.x & 63) * BT;
    const int base = r0 - HW;

    const float INV_E = 0.36787944117144233f;
    const float R     = 0.69220062755534635f;    // exp(-1/e)

    if (tid < WIN) {
        rp[tid] = __expf(-(float)tid * INV_E);
        int j = base + tid;
        wv[tid] = (j >= 0 && j < TT) ? __expf(mask[b * TT + j] * INV_E) : 0.0f;
    }
    __syncthreads();

    // ---- phase 1: fwd scan on waves 0-3, bwd scan on waves 4-7 (concurrent) ----
    if (tid < 256) {
        const int c = tid;
        const float* xb = x + (size_t)b * TT * DD + c;
        float f = 0.0f;
        #pragma unroll 8
        for (int t = 0; t < HW; ++t) {                  // top halo
            int jc = max(base + t, 0);
            f = fmaf(R, f, xb[(size_t)jc * DD] * wv[t]);
        }
        #pragma unroll 8
        for (int t = HW; t < HW + BT; ++t) {            // main rows: store F (fp32)
            int j = base + t;
            f = fmaf(R, f, xb[(size_t)j * DD] * wv[t]);
            yF[t - HW][c] = f;
        }
    } else {
        const int c = tid - 256;
        const float* xb = x + (size_t)b * TT * DD + c;
        float bb = 0.0f;
        #pragma unroll 8
        for (int t = WIN - 1; t >= HW + BT; --t) {      // bottom halo
            int jc = min(base + t, TT - 1);
            bb = fmaf(R, bb, xb[(size_t)jc * DD] * wv[t]);
        }
        #pragma unroll 8
        for (int t = HW + BT - 1; t >= HW; --t) {       // main rows: store (B - v) bf16
            int j = base + t;
            float v = xb[(size_t)j * DD] * wv[t];
            bb = fmaf(R, bb, v);
            yB[t - HW][c] = f2bf(bb - v);
        }
    }

    // attn row sums, spread over 8 waves (24 window terms each)
    {
        int row = tid & 63, q = tid >> 6;
        float s = 0.0f;
        #pragma unroll 8
        for (int tt = 0; tt < 24; ++tt) {
            int t = 24 * q + tt;
            int d = row + HW - t; d = (d < 0) ? -d : d;
            s = fmaf(rp[d], wv[t], s);
        }
        sp[q][row] = s;
    }

    // ---- phase 2 staging helper: W[:, 32c:32c+32] -> bf16 LDS [row][kc] ----
    auto stage = [&](int c, int bufsel) {
        #pragma unroll
        for (int it = 0; it < 4; ++it) {
            int e   = tid + (it << 9);
            int row = e >> 3;
            int kp  = e & 7;
            float4 w4 = *reinterpret_cast<const float4*>(&Win[row * DD + 32 * c + 4 * kp]);
            uint2 p;
            p.x = (unsigned)f2bf(w4.x) | ((unsigned)f2bf(w4.y) << 16);
            p.y = (unsigned)f2bf(w4.z) | ((unsigned)f2bf(w4.w) << 16);
            *reinterpret_cast<uint2*>(&Wl[bufsel][row][4 * kp]) = p;
        }
    };

    stage(0, 0);                       // W chunk 0 loads hide under barrier + combine
    __syncthreads();                   // scans + sp complete

    // combine: final y (bf16) = F (fp32) + (B - v) (bf16)
    #pragma unroll
    for (int e = 0; e < 32; ++e) {
        int idx = (e << 9) | tid;      // 0..16383
        int i = idx >> 8, c = idx & 255;
        yB[i][c] = f2bf(yF[i][c] + bf2f(yB[i][c]));
    }
    if (tid < BT) {
        float s = 0.0f;
        #pragma unroll
        for (int q = 0; q < 8; ++q) s += sp[q][tid];
        s_l[tid] = s;
    }
    __syncthreads();                   // yB final + Wl[0] + s_l ready

    // ---- phase 2: out[r0+i][:] = y @ Win^T + s ⊗ bin, bf16 MFMA, 8 waves ----
    const int w  = tid >> 6;
    const int lane = tid & 63;
    const int lr = lane & 15;
    const int lg = lane >> 4;
    const int wr = w >> 2;             // row-group: rows [32wr, 32wr+32)
    const int wc = w & 3;              // col-group: cols [64wc, 64wc+64)

    f32x4 acc[2][4];
    #pragma unroll
    for (int m = 0; m < 2; ++m)
        #pragma unroll
        for (int n = 0; n < 4; ++n) acc[m][n] = (f32x4){0.f, 0.f, 0.f, 0.f};

    for (int kk = 0; kk < 8; ++kk) {
        if (kk < 7) stage(kk + 1, (kk + 1) & 1);
        short8 afr[2], bfr[4];
        #pragma unroll
        for (int m = 0; m < 2; ++m)
            afr[m] = *reinterpret_cast<const short8*>(&yB[32 * wr + 16 * m + lr][kk * 32 + lg * 8]);
        #pragma unroll
        for (int n = 0; n < 4; ++n)
            bfr[n] = *reinterpret_cast<const short8*>(&Wl[kk & 1][64 * wc + 16 * n + lr][lg * 8]);
        #pragma unroll
        for (int m = 0; m < 2; ++m)
            #pragma unroll
            for (int n = 0; n < 4; ++n)
                acc[m][n] = __builtin_amdgcn_mfma_f32_16x16x32_bf16(afr[m], bfr[n], acc[m][n], 0, 0, 0);
        __syncthreads();
    }

    // epilogue: C/D map col=lane&15, row=(lane>>4)*4+j  [m89-verified]
    float bcol[4];
    #pragma unroll
    for (int n = 0; n < 4; ++n) bcol[n] = bin[64 * wc + 16 * n + lr];
    float* ob = out + ((size_t)b * TT + r0) * DD;
    #pragma unroll
    for (int m = 0; m < 2; ++m) {
        #pragma unroll
        for (int j = 0; j < 4; ++j) {
            int i = 32 * wr + 16 * m + lg * 4 + j;
            float si = s_l[i];
            #pragma unroll
            for (int n = 0; n < 4; ++n)
                ob[(size_t)i * DD + 64 * wc + 16 * n + lr] = acc[m][n][j] + si * bcol[n];
        }
    }
}

extern "C" void kernel_launch(void* const* d_in, const int* in_sizes, int n_in,
                              void* d_out, int out_size, void* d_ws, size_t ws_size,
                              hipStream_t stream) {
    const float* x    = (const float*)d_in[0];
    const float* mask = (const float*)d_in[1];
    const float* Win  = (const float*)d_in[2];
    const float* bin  = (const float*)d_in[3];
    float* out = (float*)d_out;

    const int nb = in_sizes[0] / (TT * DD);   // batches (4)
    hipLaunchKernelGGL(distattn_kernel, dim3(nb * (TT / BT)), dim3(512), 0, stream,
                       x, mask, Win, bin, out);
}